// Round 1
// baseline (88.721 us; speedup 1.0000x reference)
//
#include <hip/hip_runtime.h>
#include <math.h>

#define THREADS 256
#define CHUNK 16384
#define PER_THREAD 64   // CHUNK / THREADS
#define MAXCHUNKS 1024

// padded LDS index: one float of pad per 64 -> per-lane stride 65 -> 2-way bank conflict (free)
__device__ __forceinline__ int padidx(int i) { return i + (i >> 6); }

// Inclusive scan over 256 threads of transforms R -> g*R + v, combine(lower,upper) = (gl*gu, gu*vl+vu)
__device__ __forceinline__ void scan_compose256(double* sg, double* sv, int tid, double& mg, double& mv) {
    sg[tid] = mg; sv[tid] = mv;
    __syncthreads();
    for (int k = 1; k < THREADS; k <<= 1) {
        double og = 0.0, ov = 0.0;
        const bool has = tid >= k;
        if (has) { og = sg[tid - k]; ov = sv[tid - k]; }
        __syncthreads();
        if (has) { mv = fma(mg, ov, mv); mg = mg * og; sg[tid] = mg; sv[tid] = mv; }
        __syncthreads();
    }
}

__device__ __forceinline__ void scan_add256(double* sa, double* sb, int tid, double& a, double& b) {
    sa[tid] = a; sb[tid] = b;
    __syncthreads();
    for (int k = 1; k < THREADS; k <<= 1) {
        double oa = 0.0, ob = 0.0;
        const bool has = tid >= k;
        if (has) { oa = sa[tid - k]; ob = sb[tid - k]; }
        __syncthreads();
        if (has) { a += oa; b += ob; sa[tid] = a; sb[tid] = b; }
        __syncthreads();
    }
}

// Phase 1: per-chunk zero-init aggregates: A (end value), sum P, sum g^{k+1} P, sum P^2
__global__ __launch_bounds__(THREADS) void rs_phase1(const float* __restrict__ in,
                                                     double* __restrict__ ws, int nchunk) {
    __shared__ float sbuf[CHUNK + CHUNK / 64];
    __shared__ double sg[THREADS], sv[THREADS], sc[THREADS];
    const int tid = threadIdx.x;
    const int chunk = blockIdx.x;
    const float* src = in + (size_t)chunk * CHUNK;

    for (int i = tid * 4; i < CHUNK; i += THREADS * 4) {
        const float4 v = *(const float4*)(src + i);
        const int p = padidx(i);
        sbuf[p] = v.x; sbuf[p + 1] = v.y; sbuf[p + 2] = v.z; sbuf[p + 3] = v.w;
    }
    __syncthreads();

    const double g = 0.99;
    double p = 0.0, psum = 0.0, pq = 0.0, p2 = 0.0, gpow = 1.0;
    const int a0 = 65 * tid;
    for (int j = 0; j < PER_THREAD; ++j) {
        const double r = (double)sbuf[a0 + j];
        p = fma(g, p, r);
        gpow *= g;                 // g^{j+1}
        psum += p;
        pq = fma(gpow, p, pq);
        p2 = fma(p, p, p2);
    }
    const double g64 = gpow;       // g^64

    double mg = g64, mv = p;
    scan_compose256(sg, sv, tid, mg, mv);
    const double rho  = tid ? sv[tid - 1] : 0.0;  // zero-init incoming value for this thread
    const double gexc = tid ? sg[tid - 1] : 1.0;  // g^{64*tid}
    const double Achunk = sv[THREADS - 1];

    const double G1 = g * (1.0 - g64) / (1.0 - g);
    const double G2 = g * g * (1.0 - g64 * g64) / (1.0 - g * g);
    const double c_psum = fma(rho, G1, psum);
    const double c_pq   = gexc * fma(rho, G2, pq);
    const double c_p2   = fma(rho * rho, G2, fma(2.0 * rho, pq, p2));

    __syncthreads();
    sg[tid] = c_psum; sv[tid] = c_pq; sc[tid] = c_p2;
    __syncthreads();
    for (int k = THREADS / 2; k > 0; k >>= 1) {
        if (tid < k) { sg[tid] += sg[tid + k]; sv[tid] += sv[tid + k]; sc[tid] += sc[tid + k]; }
        __syncthreads();
    }
    if (tid == 0) {
        ws[chunk]              = Achunk;
        ws[nchunk + chunk]     = sg[0];
        ws[2 * nchunk + chunk] = sv[0];
        ws[3 * nchunk + chunk] = sc[0];
    }
}

// Phase 2: scan chunk carries (R_in per chunk) and additive scan of S1/S2 block sums
__global__ __launch_bounds__(MAXCHUNKS) void rs_phase2(double* __restrict__ ws, int nchunk) {
    __shared__ double sg[MAXCHUNKS], sv[MAXCHUNKS];
    const int t = threadIdx.x;
    const double g = 0.99;
    double gC = g;
#pragma unroll
    for (int e = 0; e < 14; ++e) gC *= gC;   // g^16384

    const bool act = t < nchunk;
    double A = 0.0, Ps = 0.0, Pq = 0.0, P2 = 0.0;
    if (act) {
        A  = ws[t];
        Ps = ws[nchunk + t];
        Pq = ws[2 * nchunk + t];
        P2 = ws[3 * nchunk + t];
    }
    double mg = act ? gC : 1.0, mv = act ? A : 0.0;
    sg[t] = mg; sv[t] = mv;
    __syncthreads();
    for (int k = 1; k < MAXCHUNKS; k <<= 1) {
        double og = 0.0, ov = 0.0;
        const bool has = t >= k;
        if (has) { og = sg[t - k]; ov = sv[t - k]; }
        __syncthreads();
        if (has) { mv = fma(mg, ov, mv); mg *= og; sg[t] = mg; sv[t] = mv; }
        __syncthreads();
    }
    const double Rin = t ? sv[t - 1] : 0.0;

    const double G1C = g * (1.0 - gC) / (1.0 - g);
    const double G2C = g * g * (1.0 - gC * gC) / (1.0 - g * g);
    double s1 = fma(Rin, G1C, Ps);
    double s2 = fma(Rin * Rin, G2C, fma(2.0 * Rin, Pq, P2));
    __syncthreads();
    sg[t] = s1; sv[t] = s2;
    __syncthreads();
    for (int k = 1; k < MAXCHUNKS; k <<= 1) {
        double oa = 0.0, ob = 0.0;
        const bool has = t >= k;
        if (has) { oa = sg[t - k]; ob = sv[t - k]; }
        __syncthreads();
        if (has) { s1 += oa; s2 += ob; sg[t] = s1; sv[t] = s2; }
        __syncthreads();
    }
    if (act) {
        ws[4 * nchunk + t] = Rin;
        ws[5 * nchunk + t] = t ? sg[t - 1] : 0.0;
        ws[6 * nchunk + t] = t ? sv[t - 1] : 0.0;
    }
}

// Phase 3: recompute local scan with true carries, emit scaled rewards
__global__ __launch_bounds__(THREADS) void rs_phase3(const float* __restrict__ in,
                                                     float* __restrict__ out,
                                                     const double* __restrict__ ws, int nchunk) {
    __shared__ float sbuf[CHUNK + CHUNK / 64];
    __shared__ double sg[THREADS], sv[THREADS];
    const int tid = threadIdx.x;
    const int chunk = blockIdx.x;
    const float* src = in + (size_t)chunk * CHUNK;

    for (int i = tid * 4; i < CHUNK; i += THREADS * 4) {
        const float4 v = *(const float4*)(src + i);
        const int p = padidx(i);
        sbuf[p] = v.x; sbuf[p + 1] = v.y; sbuf[p + 2] = v.z; sbuf[p + 3] = v.w;
    }
    __syncthreads();

    const double g = 0.99;
    double p = 0.0, psum = 0.0, pq = 0.0, p2 = 0.0, gpow = 1.0;
    const int a0 = 65 * tid;
    for (int j = 0; j < PER_THREAD; ++j) {
        const double r = (double)sbuf[a0 + j];
        p = fma(g, p, r);
        gpow *= g;
        psum += p;
        pq = fma(gpow, p, pq);
        p2 = fma(p, p, p2);
    }
    const double g64 = gpow;

    double mg = g64, mv = p;
    scan_compose256(sg, sv, tid, mg, mv);
    const double rho  = tid ? sv[tid - 1] : 0.0;
    const double gexc = tid ? sg[tid - 1] : 1.0;

    const double RinC = ws[4 * nchunk + chunk];
    const double S1C  = ws[5 * nchunk + chunk];
    const double S2C  = ws[6 * nchunk + chunk];
    const double rin  = fma(gexc, RinC, rho);   // true incoming R for this thread

    const double G1 = g * (1.0 - g64) / (1.0 - g);
    const double G2 = g * g * (1.0 - g64 * g64) / (1.0 - g * g);
    double s1 = fma(rin, G1, psum);
    double s2 = fma(rin * rin, G2, fma(2.0 * rin, pq, p2));
    __syncthreads();
    scan_add256(sg, sv, tid, s1, s2);
    double S1 = S1C + (tid ? sg[tid - 1] : 0.0);
    double S2 = S2C + (tid ? sv[tid - 1] : 0.0);

    double R = rin;
    const size_t gbase = (size_t)chunk * CHUNK + (size_t)tid * PER_THREAD;

    if (chunk == 0) {
        // precise f64 epilogue: small cnt -> catastrophic cancellation in var
        for (int j = 0; j < PER_THREAD; ++j) {
            const float rf = sbuf[a0 + j];
            R = fma(g, R, (double)rf);
            S1 += R;
            S2 = fma(R, R, S2);
            float outv;
            if (gbase + j == 0) {
                outv = rf;                      // cnt < 2 -> std = 1
            } else {
                const double cnt = (double)(gbase + j + 1);
                const double inv = 1.0 / cnt;
                const double mean = S1 * inv;
                double var = fma(S2, inv, -(mean * mean));
                var = var > 0.0 ? var : 0.0;
                double sd = sqrt(var);
                sd = sd > 1e-8 ? sd : 1e-8;
                outv = (float)((double)rf / sd);
            }
            sbuf[a0 + j] = outv;
        }
    } else {
        // cnt >= 16385: var ~ 50 >> mean^2, f32 divide/sqrt is plenty
        for (int j = 0; j < PER_THREAD; ++j) {
            const float rf = sbuf[a0 + j];
            R = fma(g, R, (double)rf);
            S1 += R;
            S2 = fma(R, R, S2);
            const float cntf = (float)(gbase + j + 1);
            const float inv = 1.0f / cntf;
            const float mean = (float)S1 * inv;
            float var = fmaf((float)S2, inv, -(mean * mean));
            var = var > 0.0f ? var : 0.0f;
            float sd = sqrtf(var);
            sd = sd > 1e-8f ? sd : 1e-8f;
            sbuf[a0 + j] = rf / sd;
        }
    }
    __syncthreads();

    float* dst = out + (size_t)chunk * CHUNK;
    for (int i = tid * 4; i < CHUNK; i += THREADS * 4) {
        const int p = padidx(i);
        *(float4*)(dst + i) = make_float4(sbuf[p], sbuf[p + 1], sbuf[p + 2], sbuf[p + 3]);
    }
}

extern "C" void kernel_launch(void* const* d_in, const int* in_sizes, int n_in,
                              void* d_out, int out_size, void* d_ws, size_t ws_size,
                              hipStream_t stream) {
    (void)n_in; (void)out_size; (void)ws_size;
    const float* in = (const float*)d_in[0];
    float* out = (float*)d_out;
    double* ws = (double*)d_ws;
    const int n = in_sizes[0];
    const int nchunk = n / CHUNK;          // 16777216 / 16384 = 1024

    rs_phase1<<<nchunk, THREADS, 0, stream>>>(in, ws, nchunk);
    rs_phase2<<<1, MAXCHUNKS, 0, stream>>>(ws, nchunk);
    rs_phase3<<<nchunk, THREADS, 0, stream>>>(in, out, ws, nchunk);
}

// Round 2
// 57.273 us; speedup vs baseline: 1.5491x; 1.5491x over previous
//
#include <hip/hip_runtime.h>
#include <math.h>

#define THREADS 256
#define GAMMA 0.99

// ---------- padded LDS index: stride PT+1 per thread (odd) -> conflict-free ----------
template<int LPT>
__device__ __forceinline__ int padi(int i) { return i + (i >> LPT); }

// ---------- block-wide exclusive scan of linear transforms x -> g*x + v ----------
// combine(lower,upper): g = gu*gl, v = gu*vl + vu. Returns exclusive (eg,ev) per thread.
// lg/lv must hold NW doubles; NW = blockDim/64. Leaves wave totals in lg/lv.
template<int NW>
__device__ __forceinline__ void block_compose_excl(int tid, double g, double v,
                                                   double& eg, double& ev,
                                                   double* lg, double* lv) {
    const int lane = tid & 63, wave = tid >> 6;
    double ig = g, iv = v;
#pragma unroll
    for (int k = 1; k < 64; k <<= 1) {
        double og = __shfl_up(ig, k);
        double ov = __shfl_up(iv, k);
        if (lane >= k) { iv = fma(ig, ov, iv); ig *= og; }
    }
    double weg = __shfl_up(ig, 1);
    double wev = __shfl_up(iv, 1);
    if (lane == 0) { weg = 1.0; wev = 0.0; }
    if (lane == 63) { lg[wave] = ig; lv[wave] = iv; }
    __syncthreads();
    double bg = 1.0, bv = 0.0;
    for (int w = 0; w < wave; ++w) { bv = fma(lg[w], bv, lv[w]); bg *= lg[w]; }
    eg = weg * bg;
    ev = fma(weg, bv, wev);
}

// ---------- block-wide exclusive additive scan of a pair ----------
template<int NW>
__device__ __forceinline__ void block_add_excl2(int tid, double a, double b,
                                                double& ea, double& eb,
                                                double* la, double* lb) {
    const int lane = tid & 63, wave = tid >> 6;
    double ia = a, ib = b;
#pragma unroll
    for (int k = 1; k < 64; k <<= 1) {
        double oa = __shfl_up(ia, k);
        double ob = __shfl_up(ib, k);
        if (lane >= k) { ia += oa; ib += ob; }
    }
    double wea = __shfl_up(ia, 1);
    double web = __shfl_up(ib, 1);
    if (lane == 0) { wea = 0.0; web = 0.0; }
    if (lane == 63) { la[wave] = ia; lb[wave] = ib; }
    __syncthreads();
    double ba = 0.0, bb = 0.0;
    for (int w = 0; w < wave; ++w) { ba += la[w]; bb += lb[w]; }
    ea = wea + ba;
    eb = web + bb;
}

// ---------- Phase 1: per-chunk zero-init aggregates (A, sumP, sum g^{k+1}P, sumP^2) ----------
template<int PT, int LPT>
__global__ __launch_bounds__(THREADS) void rs_phase1(const float* __restrict__ in,
                                                     double* __restrict__ ws, int nchunk) {
    constexpr int CHUNKE = THREADS * PT;
    __shared__ double lg[4], lv[4], r1[4], r2[4], r3[4];
    const int tid = threadIdx.x, lane = tid & 63, wave = tid >> 6;
    const int chunk = blockIdx.x;
    const float* src = in + (size_t)chunk * CHUNKE + (size_t)tid * PT;

    float rv[PT];
#pragma unroll
    for (int q = 0; q < PT / 4; ++q) {
        const float4 t = ((const float4*)src)[q];
        rv[4 * q] = t.x; rv[4 * q + 1] = t.y; rv[4 * q + 2] = t.z; rv[4 * q + 3] = t.w;
    }
    const float gf = (float)GAMMA;
    float p = 0.f, psum = 0.f, pq = 0.f, p2 = 0.f, gp = 1.f;
#pragma unroll
    for (int j = 0; j < PT; ++j) {
        p = fmaf(gf, p, rv[j]);
        gp *= gf;
        psum += p;
        pq = fmaf(gp, p, pq);
        p2 = fmaf(p, p, p2);
    }
    const double g = GAMMA;
    double gPT = g;
#pragma unroll
    for (int e = 0; e < LPT; ++e) gPT *= gPT;   // g^PT

    double eg, ev;
    block_compose_excl<4>(tid, gPT, (double)p, eg, ev, lg, lv);
    const double rho = ev, gexc = eg;

    const double G1 = g * (1.0 - gPT) / (1.0 - g);
    const double G2 = g * g * (1.0 - gPT * gPT) / (1.0 - g * g);
    double c1 = fma(rho, G1, (double)psum);
    double c2 = gexc * fma(rho, G2, (double)pq);
    double c3 = fma(rho * rho, G2, fma(2.0 * rho, (double)pq, (double)p2));
#pragma unroll
    for (int k = 32; k > 0; k >>= 1) {
        c1 += __shfl_down(c1, k);
        c2 += __shfl_down(c2, k);
        c3 += __shfl_down(c3, k);
    }
    if (lane == 0) { r1[wave] = c1; r2[wave] = c2; r3[wave] = c3; }
    __syncthreads();
    if (tid == 0) {
        double A = 0.0;
#pragma unroll
        for (int w = 0; w < 4; ++w) A = fma(lg[w], A, lv[w]);
        ws[chunk]              = A;
        ws[nchunk + chunk]     = r1[0] + r1[1] + r1[2] + r1[3];
        ws[2 * nchunk + chunk] = r2[0] + r2[1] + r2[2] + r2[3];
        ws[3 * nchunk + chunk] = r3[0] + r3[1] + r3[2] + r3[3];
    }
}

// ---------- Phase 2: scan chunk carries; emit per-chunk Rin + exclusive S1/S2 ----------
template<int CPT, int LOG2CHUNK>
__global__ __launch_bounds__(1024) void rs_phase2(double* __restrict__ ws, int nchunk) {
    __shared__ double lg[16], lv[16], la[16], lb[16];
    const int t = threadIdx.x;
    const double g = GAMMA;
    double gC = g;
#pragma unroll
    for (int e = 0; e < LOG2CHUNK; ++e) gC *= gC;   // g^CHUNK

    double A[CPT], Ps[CPT], Pq[CPT], P2[CPT];
    const int c0 = t * CPT;
#pragma unroll
    for (int i = 0; i < CPT; ++i) {
        const int c = c0 + i;
        const bool ok = c < nchunk;
        A[i]  = ok ? ws[c] : 0.0;
        Ps[i] = ok ? ws[nchunk + c] : 0.0;
        Pq[i] = ok ? ws[2 * nchunk + c] : 0.0;
        P2[i] = ok ? ws[3 * nchunk + c] : 0.0;
    }
    double mg = 1.0, mv = 0.0;
#pragma unroll
    for (int i = 0; i < CPT; ++i) { mv = fma(gC, mv, A[i]); mg *= gC; }

    double eg, ev;
    block_compose_excl<16>(t, mg, mv, eg, ev, lg, lv);

    const double G1C = g * (1.0 - gC) / (1.0 - g);
    const double G2C = g * g * (1.0 - gC * gC) / (1.0 - g * g);
    double Rin[CPT + 1];
    Rin[0] = ev;
    double s1[CPT], s2[CPT];
#pragma unroll
    for (int i = 0; i < CPT; ++i) {
        s1[i] = fma(Rin[i], G1C, Ps[i]);
        s2[i] = fma(Rin[i] * Rin[i], G2C, fma(2.0 * Rin[i], Pq[i], P2[i]));
        Rin[i + 1] = fma(gC, Rin[i], A[i]);
    }
    double ts1 = 0.0, ts2 = 0.0;
#pragma unroll
    for (int i = 0; i < CPT; ++i) { ts1 += s1[i]; ts2 += s2[i]; }
    double ea, eb;
    block_add_excl2<16>(t, ts1, ts2, ea, eb, la, lb);
#pragma unroll
    for (int i = 0; i < CPT; ++i) {
        const int c = c0 + i;
        if (c < nchunk) {
            ws[4 * nchunk + c] = Rin[i];
            ws[5 * nchunk + c] = ea;
            ws[6 * nchunk + c] = eb;
        }
        ea += s1[i];
        eb += s2[i];
    }
}

// ---------- Phase 3: rebase with true carries, emit scaled rewards ----------
template<int PT, int LPT>
__global__ __launch_bounds__(THREADS) void rs_phase3(const float* __restrict__ in,
                                                     float* __restrict__ out,
                                                     const double* __restrict__ ws, int nchunk) {
    constexpr int CHUNKE = THREADS * PT;
    __shared__ float sbuf[CHUNKE + THREADS];     // +1 float pad per PT -> stride PT+1 (odd)
    __shared__ double lg[4], lv[4], la[4], lb[4];
    const int tid = threadIdx.x;
    const int chunk = blockIdx.x;
    const float* src = in + (size_t)chunk * CHUNKE + (size_t)tid * PT;

    float rv[PT];
#pragma unroll
    for (int q = 0; q < PT / 4; ++q) {
        const float4 t = ((const float4*)src)[q];
        rv[4 * q] = t.x; rv[4 * q + 1] = t.y; rv[4 * q + 2] = t.z; rv[4 * q + 3] = t.w;
    }
    const float gf = (float)GAMMA;
    float p = 0.f, psum = 0.f, pq = 0.f, p2 = 0.f, gp = 1.f;
#pragma unroll
    for (int j = 0; j < PT; ++j) {
        p = fmaf(gf, p, rv[j]);
        gp *= gf;
        psum += p;
        pq = fmaf(gp, p, pq);
        p2 = fmaf(p, p, p2);
    }
    const double g = GAMMA;
    double gPT = g;
#pragma unroll
    for (int e = 0; e < LPT; ++e) gPT *= gPT;

    double eg, ev;
    block_compose_excl<4>(tid, gPT, (double)p, eg, ev, lg, lv);

    const double RinC = ws[4 * nchunk + chunk];
    const double S1C  = ws[5 * nchunk + chunk];
    const double S2C  = ws[6 * nchunk + chunk];
    const double rin  = fma(eg, RinC, ev);      // true incoming R for this thread's segment

    const double G1 = g * (1.0 - gPT) / (1.0 - g);
    const double G2 = g * g * (1.0 - gPT * gPT) / (1.0 - g * g);
    const double s1 = fma(rin, G1, (double)psum);
    const double s2 = fma(rin * rin, G2, fma(2.0 * rin, (double)pq, (double)p2));
    double ea, eb;
    block_add_excl2<4>(tid, s1, s2, ea, eb, la, lb);
    const double S1b = S1C + ea;
    const double S2b = S2C + eb;

    const int a0 = padi<LPT>(tid * PT);          // = tid*(PT+1)

    if (chunk == 0) {
        // precise f64 epilogue for the small-cnt region (cancellation-sensitive)
        double R = rin, S1 = S1b, S2 = S2b;
        const size_t gbase = (size_t)tid * PT;
        for (int j = 0; j < PT; ++j) {
            const float rf = rv[j];
            R = fma(g, R, (double)rf);
            S1 += R;
            S2 = fma(R, R, S2);
            float ov;
            if (gbase + j == 0) {
                ov = rf;                         // cnt < 2 -> std = 1
            } else {
                const double cnt = (double)(gbase + j + 1);
                const double inv = 1.0 / cnt;
                const double mean = S1 * inv;
                double var = fma(S2, inv, -(mean * mean));
                var = var > 0.0 ? var : 0.0;
                double sd = sqrt(var);
                sd = sd > 1e-8 ? sd : 1e-8;
                ov = (float)((double)rf / sd);
            }
            sbuf[a0 + j] = ov;
        }
    } else {
        // cnt >= CHUNK+1: var ~ stationary (~50) >> mean^2 -> f32 is plenty
        float R = (float)rin;
        float ls1 = 0.f, ls2 = 0.f;
        const float S1bf = (float)S1b, S2bf = (float)S2b;
        const float base_cnt = (float)((size_t)chunk * CHUNKE + (size_t)tid * PT);
#pragma unroll
        for (int j = 0; j < PT; ++j) {
            const float rf = rv[j];
            R = fmaf(gf, R, rf);
            ls1 += R;
            ls2 = fmaf(R, R, ls2);
            const float cnt = base_cnt + (float)(j + 1);
            const float inv = 1.0f / cnt;
            const float S1f = S1bf + ls1;
            const float S2f = S2bf + ls2;
            const float mean = S1f * inv;
            float var = fmaf(S2f, inv, -(mean * mean));
            var = var > 0.f ? var : 0.f;
            float sd = sqrtf(var);
            sd = sd > 1e-8f ? sd : 1e-8f;
            sbuf[a0 + j] = rf / sd;
        }
    }
    __syncthreads();

    float* dst = out + (size_t)chunk * CHUNKE;
    for (int i = tid * 4; i < CHUNKE; i += THREADS * 4) {
        const int pp = padi<LPT>(i);
        *(float4*)(dst + i) = make_float4(sbuf[pp], sbuf[pp + 1], sbuf[pp + 2], sbuf[pp + 3]);
    }
}

extern "C" void kernel_launch(void* const* d_in, const int* in_sizes, int n_in,
                              void* d_out, int out_size, void* d_ws, size_t ws_size,
                              hipStream_t stream) {
    (void)n_in; (void)out_size;
    const float* in = (const float*)d_in[0];
    float* out = (float*)d_out;
    double* ws = (double*)d_ws;
    const int n = in_sizes[0];

    const int nc16 = n / 4096;
    if ((n % 4096) == 0 && nc16 >= 1 && nc16 <= 4096 &&
        ws_size >= (size_t)7 * (size_t)nc16 * sizeof(double)) {
        rs_phase1<16, 4><<<nc16, THREADS, 0, stream>>>(in, ws, nc16);
        rs_phase2<4, 12><<<1, 1024, 0, stream>>>(ws, nc16);
        rs_phase3<16, 4><<<nc16, THREADS, 0, stream>>>(in, out, ws, nc16);
    } else {
        const int nc64 = n / 16384;
        rs_phase1<64, 6><<<nc64, THREADS, 0, stream>>>(in, ws, nc64);
        rs_phase2<1, 14><<<1, 1024, 0, stream>>>(ws, nc64);
        rs_phase3<64, 6><<<nc64, THREADS, 0, stream>>>(in, out, ws, nc64);
    }
}